// Round 1
// baseline (216.187 us; speedup 1.0000x reference)
//
#include <hip/hip_runtime.h>
#include <math.h>

#define LN_EPS 1e-5f

constexpr int D = 512;
constexpr int DC = 16;
constexpr int K = 8192;
constexpr int NTOK = 16384;      // 8 * 2048
constexpr int KSPLIT = 8;
constexpr int KCHUNK = K / KSPLIT; // 1024

// ---------------------------------------------------------------------------
// Kernel 1: prep codebook. cb2n[k][d] = -2*cb[k][d]; c2[k] = sum_d cb[k][d]^2
// ---------------------------------------------------------------------------
__global__ __launch_bounds__(256) void prep_cb(const float* __restrict__ cb,
                                               float* __restrict__ cb2n,
                                               float* __restrict__ c2) {
  int k = blockIdx.x * 256 + threadIdx.x;
  if (k >= K) return;
  const float4* src = (const float4*)(cb + (size_t)k * DC);
  float4 a = src[0], b = src[1], c = src[2], d = src[3];
  float s0 = (a.x * a.x + a.y * a.y) + (a.z * a.z + a.w * a.w);
  float s1 = (b.x * b.x + b.y * b.y) + (b.z * b.z + b.w * b.w);
  float s2 = (c.x * c.x + c.y * c.y) + (c.z * c.z + c.w * c.w);
  float s3 = (d.x * d.x + d.y * d.y) + (d.z * d.z + d.w * d.w);
  float s = (s0 + s1) + (s2 + s3);
  float4* dst = (float4*)(cb2n + (size_t)k * DC);
  dst[0] = make_float4(-2.f * a.x, -2.f * a.y, -2.f * a.z, -2.f * a.w);
  dst[1] = make_float4(-2.f * b.x, -2.f * b.y, -2.f * b.z, -2.f * b.w);
  dst[2] = make_float4(-2.f * c.x, -2.f * c.y, -2.f * c.z, -2.f * c.w);
  dst[3] = make_float4(-2.f * d.x, -2.f * d.y, -2.f * d.z, -2.f * d.w);
  c2[k] = s;
}

// ---------------------------------------------------------------------------
// Kernel 2: projection + LayerNorm.
// Block = 256 threads handles 16 tokens. thread -> (tok = tid>>4, c = tid&15).
// x rows staged in LDS (32KB); W staged in LDS with pitch 516 (conflict-free).
// LN over the 16 c-lanes via shfl_xor (width 16).
// ---------------------------------------------------------------------------
__global__ __launch_bounds__(256) void proj_ln(const float* __restrict__ x,
                                               const float* __restrict__ w,
                                               float* __restrict__ h) {
  __shared__ float xs[16 * 512];    // 32 KB
  __shared__ float wsh[16 * 516];   // 33 KB, padded pitch
  const int tid = threadIdx.x;
  const size_t base = (size_t)blockIdx.x * (16 * 512);

  const float4* xg = (const float4*)(x + base);
  float4* xs4 = (float4*)xs;
#pragma unroll
  for (int i = 0; i < 8; ++i) xs4[tid + 256 * i] = xg[tid + 256 * i];

  const float4* wg = (const float4*)w;
#pragma unroll
  for (int i = 0; i < 8; ++i) {
    int idx = tid + 256 * i;   // float4 index, 0..2047
    int c = idx >> 7;          // / 128 float4-per-row
    int d4 = idx & 127;
    *(float4*)&wsh[c * 516 + d4 * 4] = wg[idx];
  }
  __syncthreads();

  const int tok = tid >> 4;
  const int c = tid & 15;
  const float4* xr = (const float4*)(xs + tok * 512);
  const float4* wr = (const float4*)(wsh + c * 516);
  float acc0 = 0.f, acc1 = 0.f, acc2 = 0.f, acc3 = 0.f;
#pragma unroll 16
  for (int d4 = 0; d4 < 128; ++d4) {
    float4 xv = xr[d4];
    float4 wv = wr[d4];
    acc0 = fmaf(xv.x, wv.x, acc0);
    acc1 = fmaf(xv.y, wv.y, acc1);
    acc2 = fmaf(xv.z, wv.z, acc2);
    acc3 = fmaf(xv.w, wv.w, acc3);
  }
  float hv = (acc0 + acc1) + (acc2 + acc3);

  // LayerNorm across the 16 lanes that share a token
  float s = hv;
  s += __shfl_xor(s, 1, 16);
  s += __shfl_xor(s, 2, 16);
  s += __shfl_xor(s, 4, 16);
  s += __shfl_xor(s, 8, 16);
  float mu = s * (1.f / 16.f);
  float diff = hv - mu;
  float v = diff * diff;
  v += __shfl_xor(v, 1, 16);
  v += __shfl_xor(v, 2, 16);
  v += __shfl_xor(v, 4, 16);
  v += __shfl_xor(v, 8, 16);
  float var = v * (1.f / 16.f);
  float outv = diff / sqrtf(var + LN_EPS);

  h[((size_t)blockIdx.x * 16 + tok) * 16 + c] = outv;
}

// ---------------------------------------------------------------------------
// Kernel 3: per-chunk argmin. One token per lane; codebook rows are
// wave-uniform -> scalar loads. dist' = c2[k] + sum_d h[d]*(-2*cb[k][d])
// (h2 dropped: constant per token, doesn't change argmin).
// Grid: (NTOK/256, KSPLIT).
// ---------------------------------------------------------------------------
__global__ __launch_bounds__(256) void argmin_chunk(
    const float* __restrict__ h, const float* __restrict__ cb2n,
    const float* __restrict__ c2, float* __restrict__ pd,
    int* __restrict__ pi) {
  const int tid = threadIdx.x;
  const int token = blockIdx.x * 256 + tid;
  const int k0 = blockIdx.y * KCHUNK;

  const float4* hr = (const float4*)(h + (size_t)token * DC);
  float4 h0 = hr[0], h1 = hr[1], h2 = hr[2], h3 = hr[3];

  float best = 3.0e38f;
  int bidx = k0;
#pragma unroll 2
  for (int kk = 0; kk < KCHUNK; ++kk) {
    const int k = k0 + kk;
    const float4* cr = (const float4*)(cb2n + k * DC);
    float4 c0 = cr[0], c1 = cr[1], c4 = cr[2], c3 = cr[3];
    float acc = c2[k];
    acc = fmaf(h0.x, c0.x, acc);
    acc = fmaf(h0.y, c0.y, acc);
    acc = fmaf(h0.z, c0.z, acc);
    acc = fmaf(h0.w, c0.w, acc);
    acc = fmaf(h1.x, c1.x, acc);
    acc = fmaf(h1.y, c1.y, acc);
    acc = fmaf(h1.z, c1.z, acc);
    acc = fmaf(h1.w, c1.w, acc);
    acc = fmaf(h2.x, c4.x, acc);
    acc = fmaf(h2.y, c4.y, acc);
    acc = fmaf(h2.z, c4.z, acc);
    acc = fmaf(h2.w, c4.w, acc);
    acc = fmaf(h3.x, c3.x, acc);
    acc = fmaf(h3.y, c3.y, acc);
    acc = fmaf(h3.z, c3.z, acc);
    acc = fmaf(h3.w, c3.w, acc);
    if (acc < best) {
      best = acc;
      bidx = k;
    }
  }
  pd[(size_t)blockIdx.y * NTOK + token] = best;
  pi[(size_t)blockIdx.y * NTOK + token] = bidx;
}

// ---------------------------------------------------------------------------
// Kernel 4: reduce the KSPLIT partials per token. Ascending chunk order with
// strict < keeps the lowest index on exact ties (numpy argmin semantics).
// ---------------------------------------------------------------------------
__global__ __launch_bounds__(256) void reduce_parts(
    const float* __restrict__ pd, const int* __restrict__ pi,
    int* __restrict__ out) {
  int token = blockIdx.x * 256 + threadIdx.x;
  float best = pd[token];
  int bi = pi[token];
#pragma unroll
  for (int kc = 1; kc < KSPLIT; ++kc) {
    float dv = pd[(size_t)kc * NTOK + token];
    int i2 = pi[(size_t)kc * NTOK + token];
    if (dv < best) {
      best = dv;
      bi = i2;
    }
  }
  out[token] = bi;
}

// ---------------------------------------------------------------------------
extern "C" void kernel_launch(void* const* d_in, const int* in_sizes, int n_in,
                              void* d_out, int out_size, void* d_ws,
                              size_t ws_size, hipStream_t stream) {
  const float* x = (const float*)d_in[0];       // (8,2048,512)
  const float* w = (const float*)d_in[1];       // (16,512)
  const float* cb = (const float*)d_in[2];      // (8192,16)

  float* ws = (float*)d_ws;
  float* h = ws;                                 // NTOK*DC      = 262144
  float* cb2n = h + (size_t)NTOK * DC;           // K*DC         = 131072
  float* c2 = cb2n + (size_t)K * DC;             // K            = 8192
  float* pd = c2 + K;                            // KSPLIT*NTOK  = 131072
  int* pi = (int*)(pd + (size_t)KSPLIT * NTOK);  // KSPLIT*NTOK  = 131072

  prep_cb<<<K / 256, 256, 0, stream>>>(cb, cb2n, c2);
  proj_ln<<<NTOK / 16, 256, 0, stream>>>(x, w, h);
  argmin_chunk<<<dim3(NTOK / 256, KSPLIT), 256, 0, stream>>>(h, cb2n, c2, pd,
                                                             pi);
  reduce_parts<<<NTOK / 256, 256, 0, stream>>>(pd, pi, (int*)d_out);
}

// Round 2
// 59.573 us; speedup vs baseline: 3.6289x; 3.6289x over previous
//
#include <hip/hip_runtime.h>
#include <math.h>

#define LN_EPS 1e-5f

typedef _Float16 f16;
typedef _Float16 f16x8 __attribute__((ext_vector_type(8)));
typedef _Float16 f16x2 __attribute__((ext_vector_type(2)));
typedef float f32x4 __attribute__((ext_vector_type(4)));
typedef unsigned long long ull;

constexpr int DC = 16;
constexpr int K = 8192;
constexpr int NTOK = 16384;          // 8*2048
constexpr int KSPLIT = 16;
constexpr int KCHUNK = K / KSPLIT;   // 512 codes per block
constexpr int CH = 128;              // codes per staged sub-chunk (8 tiles)
constexpr int NCH = KCHUNK / CH;     // 4
constexpr float SCALE = 16384.f;     // SH(256) * SC(64), exact powers of 2

// ---------------------------------------------------------------------------
// Kernel 1: prep codebook into MFMA-A fragment order (fp16 hi/lo split) + c2.
// A-frag layout per 16-code tile: lane l holds 8 halves, slot s=(l>>4)*8+p.
// Logical slots: s<16 -> hi(c[-128*cb] dim s), s>=16 -> lo(dim s-16).
// cbA[(tile*64 + lane)*8 + p], contiguous 16B per lane.
// c2s[code] = (sum(cb^2) + 16) * SCALE   (fp32, exact scale)
// ---------------------------------------------------------------------------
__global__ __launch_bounds__(256) void prep_cb(const float* __restrict__ cb,
                                               f16* __restrict__ cbA,
                                               float* __restrict__ c2s) {
  const int i = threadIdx.x;
  const int ti = i >> 6;          // tile within block (0..3)
  const int l = i & 63;           // lane role
  const int ct = blockIdx.x * 4 + ti;       // global code-tile
  const int code = ct * 16 + (l & 15);
  const int g = l >> 4;                      // slot group 0..3

  const float* row = cb + (size_t)code * DC + (g & 1) * 8;  // dims 0-7 or 8-15
  f32x4 v0 = *(const f32x4*)row;
  f32x4 v1 = *(const f32x4*)(row + 4);
  float vv[8] = {v0[0], v0[1], v0[2], v0[3], v1[0], v1[1], v1[2], v1[3]};

  f16x8 r;
#pragma unroll
  for (int p = 0; p < 8; ++p) {
    float cc = -128.f * vv[p];     // (-2*cb) * 64, exact pow2 scaling
    f16 hh = (f16)cc;
    r[p] = (g < 2) ? hh : (f16)(cc - (float)hh);
  }
  *(f16x8*)(cbA + ((size_t)ct * 64 + l) * 8) = r;

  if (g == 0) {
    const f32x4* rw = (const f32x4*)(cb + (size_t)code * DC);
    f32x4 a0 = rw[0], a1 = rw[1], a2 = rw[2], a3 = rw[3];
    float s = 0.f;
#pragma unroll
    for (int p = 0; p < 4; ++p)
      s += a0[p] * a0[p] + a1[p] * a1[p] + a2[p] * a2[p] + a3[p] * a3[p];
    c2s[code] = (s + 16.f) * SCALE;
  }
}

// ---------------------------------------------------------------------------
// Kernel 2: projection + LayerNorm, emits h in MFMA-B fragment order, fp16
// hi/lo split, scaled by 256 (exact). Block = 16 tokens = one B token-tile.
// B-frag: lane l holds slots s=(l>>4)*8+p for col=l&15 (token).
// Logical: s<16 -> hi(256*h dim s), s>=16 -> lo(dim s-16).
// ---------------------------------------------------------------------------
__global__ __launch_bounds__(256) void proj_ln(const float* __restrict__ x,
                                               const float* __restrict__ w,
                                               f16* __restrict__ hB) {
  __shared__ float xs[16 * 512];    // 32 KB
  __shared__ float wsh[16 * 516];   // ~33 KB, padded pitch
  __shared__ float hsm[16][17];
  const int tid = threadIdx.x;
  const size_t base = (size_t)blockIdx.x * (16 * 512);

  const float4* xg = (const float4*)(x + base);
  float4* xs4 = (float4*)xs;
#pragma unroll
  for (int i = 0; i < 8; ++i) xs4[tid + 256 * i] = xg[tid + 256 * i];

  const float4* wg = (const float4*)w;
#pragma unroll
  for (int i = 0; i < 8; ++i) {
    int idx = tid + 256 * i;   // float4 index, 0..2047
    int c = idx >> 7;
    int d4 = idx & 127;
    *(float4*)&wsh[c * 516 + d4 * 4] = wg[idx];
  }
  __syncthreads();

  const int tok = tid >> 4;
  const int c = tid & 15;
  const float4* xr = (const float4*)(xs + tok * 512);
  const float4* wr = (const float4*)(wsh + c * 516);
  float acc0 = 0.f, acc1 = 0.f, acc2 = 0.f, acc3 = 0.f;
#pragma unroll 16
  for (int d4 = 0; d4 < 128; ++d4) {
    float4 xv = xr[d4];
    float4 wv = wr[d4];
    acc0 = fmaf(xv.x, wv.x, acc0);
    acc1 = fmaf(xv.y, wv.y, acc1);
    acc2 = fmaf(xv.z, wv.z, acc2);
    acc3 = fmaf(xv.w, wv.w, acc3);
  }
  float hv = (acc0 + acc1) + (acc2 + acc3);

  float s = hv;
  s += __shfl_xor(s, 1, 16);
  s += __shfl_xor(s, 2, 16);
  s += __shfl_xor(s, 4, 16);
  s += __shfl_xor(s, 8, 16);
  float mu = s * (1.f / 16.f);
  float diff = hv - mu;
  float v = diff * diff;
  v += __shfl_xor(v, 1, 16);
  v += __shfl_xor(v, 2, 16);
  v += __shfl_xor(v, 4, 16);
  v += __shfl_xor(v, 8, 16);
  float var = v * (1.f / 16.f);
  hsm[tok][c] = diff / sqrtf(var + LN_EPS);
  __syncthreads();

  // emit B fragment: thread -> (lane l = tid>>2, pair q = tid&3)
  const int l = tid >> 2;
  const int q = tid & 3;
  const int col = l & 15;
  const int g = l >> 4;
  const int s0 = g * 8 + q * 2;
  f16x2 u;
#pragma unroll
  for (int e = 0; e < 2; ++e) {
    int sE = s0 + e;
    int d = sE & 15;
    float f = hsm[col][d] * 256.f;   // exact pow2 scale
    f16 hh = (f16)f;
    u[e] = (sE < 16) ? hh : (f16)(f - (float)hh);
  }
  *(f16x2*)(hB + ((size_t)blockIdx.x * 64 + l) * 8 + q * 2) = u;
}

// ---------------------------------------------------------------------------
// Kernel 3: MFMA argmin. Block = 4 waves x 4 token-tiles each (256 tokens),
// all waves iterate the same KCHUNK codes (LDS-staged, double-buffered via
// global_load_lds). Per code-tile: acc = mfma(a, b1, c2) ; acc = mfma(a, b2,
// acc) -> exact (hi+lo)x(hi+lo) product. Running (best,bidx) per lane, merged
// across lane groups by shfl_xor, then packed u64 atomicMin across splits.
// ---------------------------------------------------------------------------
__global__ __launch_bounds__(256, 4) void argmin_mfma(
    const f16* __restrict__ cbA, const float* __restrict__ c2s,
    const f16* __restrict__ hB, ull* __restrict__ keys) {
  __shared__ f16 lA[2][CH * 32];   // 2 x 8 KB
  __shared__ float c2l[KCHUNK];    // 2 KB
  const int tid = threadIdx.x;
  const int w = tid >> 6;
  const int lane = tid & 63;
  const int kt0 = blockIdx.y * (KCHUNK / 16);  // first code-tile of split

  // stage this split's c2 (512 floats) once
  *(float2*)&c2l[tid * 2] =
      *(const float2*)&c2s[blockIdx.y * KCHUNK + tid * 2];

  // B fragments: 4 token-tiles per wave; b2 = b1 loaded at lane^32 (=[lo|hi])
  f16x8 b1[4], b2[4];
  int ttg[4];
#pragma unroll
  for (int j = 0; j < 4; ++j) {
    ttg[j] = blockIdx.x * 16 + w * 4 + j;
    b1[j] = *(const f16x8*)&hB[((size_t)ttg[j] * 64 + lane) * 8];
    b2[j] = *(const f16x8*)&hB[((size_t)ttg[j] * 64 + (lane ^ 32)) * 8];
  }

  float best[4] = {3.0e38f, 3.0e38f, 3.0e38f, 3.0e38f};
  int bidx[4] = {0, 0, 0, 0};

  auto stage = [&](int buf, int ch) {
    const char* g = (const char*)(cbA + (size_t)(kt0 + ch * 8) * 64 * 8);
    char* lbase = (char*)&lA[buf][0];
#pragma unroll
    for (int r = 0; r < 2; ++r) {
      int bo = (r * 4 + w) * 1024 + lane * 16;
      __builtin_amdgcn_global_load_lds(
          (const __attribute__((address_space(1))) void*)(g + bo),
          (__attribute__((address_space(3))) void*)(lbase + bo), 16, 0, 0);
    }
  };

  stage(0, 0);
  for (int ch = 0; ch < NCH; ++ch) {
    __syncthreads();  // compiler drains vmcnt+lgkmcnt before s_barrier
    if (ch + 1 < NCH) stage((ch + 1) & 1, ch + 1);
    const int buf = ch & 1;
    for (int t = 0; t < 8; ++t) {
      f16x8 a = *(const f16x8*)&lA[buf][(t * 64 + lane) * 8];
      const int lk = ch * CH + t * 16 + (lane >> 4) * 4;
      f32x4 c2v = *(const f32x4*)&c2l[lk];
      const int ib = blockIdx.y * KCHUNK + lk;
#pragma unroll
      for (int j = 0; j < 4; ++j) {
        f32x4 acc =
            __builtin_amdgcn_mfma_f32_16x16x32_f16(a, b1[j], c2v, 0, 0, 0);
        acc = __builtin_amdgcn_mfma_f32_16x16x32_f16(a, b2[j], acc, 0, 0, 0);
#pragma unroll
        for (int r = 0; r < 4; ++r) {
          bool lt = acc[r] < best[j];     // strict <, ascending k order
          best[j] = lt ? acc[r] : best[j];
          bidx[j] = lt ? (ib + r) : bidx[j];
        }
      }
    }
  }

  // merge the 4 lane-groups (rows) per token column, then global atomicMin
#pragma unroll
  for (int j = 0; j < 4; ++j) {
    float d = best[j];
    int ix = bidx[j];
#pragma unroll
    for (int off = 16; off <= 32; off <<= 1) {
      float od = __shfl_xor(d, off);
      int oi = __shfl_xor(ix, off);
      bool take = (od < d) || (od == d && oi < ix);
      d = take ? od : d;
      ix = take ? oi : ix;
    }
    d = fmaxf(d, 0.f);  // keep sign bit clear for monotone bit-packing
    if (lane < 16) {
      ull key = ((ull)__float_as_uint(d) << 32) | (unsigned)ix;
      atomicMin(&keys[ttg[j] * 16 + lane], key);
    }
  }
}

// ---------------------------------------------------------------------------
// Kernel 4: unpack code index from packed key.
// ---------------------------------------------------------------------------
__global__ __launch_bounds__(256) void finalize(const ull* __restrict__ keys,
                                                int* __restrict__ out) {
  int t = blockIdx.x * 256 + threadIdx.x;
  out[t] = (int)(unsigned)(keys[t] & 0xFFFFFFFFull);
}

// ---------------------------------------------------------------------------
extern "C" void kernel_launch(void* const* d_in, const int* in_sizes, int n_in,
                              void* d_out, int out_size, void* d_ws,
                              size_t ws_size, hipStream_t stream) {
  const float* x = (const float*)d_in[0];    // (8,2048,512)
  const float* w = (const float*)d_in[1];    // (16,512)
  const float* cb = (const float*)d_in[2];   // (8192,16)

  f16* cbA = (f16*)d_ws;                         // 8192*32 halves = 512 KB
  float* c2s = (float*)(cbA + (size_t)K * 32);   // 32 KB
  f16* hB = (f16*)(c2s + K);                     // 16384*32 halves = 1 MB
  ull* keys = (ull*)(hB + (size_t)NTOK * 32);    // 128 KB

  hipMemsetAsync(keys, 0xFF, (size_t)NTOK * sizeof(ull), stream);
  prep_cb<<<K / 64, 256, 0, stream>>>(cb, cbA, c2s);
  proj_ln<<<NTOK / 16, 256, 0, stream>>>(x, w, hB);
  argmin_mfma<<<dim3(NTOK / 256, KSPLIT), 256, 0, stream>>>(cbA, c2s, hB,
                                                            keys);
  finalize<<<NTOK / 256, 256, 0, stream>>>(keys, (int*)d_out);
}

// Round 3
// 57.418 us; speedup vs baseline: 3.7651x; 1.0375x over previous
//
#include <hip/hip_runtime.h>
#include <math.h>

#define LN_EPS 1e-5f

typedef _Float16 f16;
typedef _Float16 f16x8 __attribute__((ext_vector_type(8)));
typedef _Float16 f16x2 __attribute__((ext_vector_type(2)));
typedef float f32x4 __attribute__((ext_vector_type(4)));
typedef unsigned long long ull;

constexpr int DC = 16;
constexpr int K = 8192;
constexpr int NTOK = 16384;          // 8*2048
constexpr int KSPLIT = 16;
constexpr int KCHUNK = K / KSPLIT;   // 512 codes per block
constexpr int CH = 128;              // codes per staged sub-chunk (8 tiles)
constexpr int NCH = KCHUNK / CH;     // 4
constexpr float SCALE = 16384.f;     // SH(256) * SC(64), exact powers of 2

// ---------------------------------------------------------------------------
// Kernel 1: prep codebook into MFMA-A fragment order (fp16 hi/lo split) + c2.
// Also initializes the packed argmin keys (replaces a pathologically slow
// 128KB hipMemsetAsync dispatch that cost ~41us per replay).
// A-frag layout per 16-code tile: lane l holds 8 halves, slot s=(l>>4)*8+p.
// Logical slots: s<16 -> hi(c[-128*cb] dim s), s>=16 -> lo(dim s-16).
// c2s[code] = (sum(cb^2) + 16.5) * SCALE  (fp32; +16.5 > h2 keeps dist > 0)
// ---------------------------------------------------------------------------
__global__ __launch_bounds__(256) void prep_cb(const float* __restrict__ cb,
                                               f16* __restrict__ cbA,
                                               float* __restrict__ c2s,
                                               ull* __restrict__ keys) {
  const int gt = blockIdx.x * 256 + threadIdx.x;
  if (gt < NTOK) keys[gt] = ~0ULL;   // init packed (dist,idx) keys

  const int i = threadIdx.x;
  const int ti = i >> 6;          // tile within block (0..3)
  const int l = i & 63;           // lane role
  const int ct = blockIdx.x * 4 + ti;       // global code-tile
  const int code = ct * 16 + (l & 15);
  const int g = l >> 4;                      // slot group 0..3

  const float* row = cb + (size_t)code * DC + (g & 1) * 8;  // dims 0-7 / 8-15
  f32x4 v0 = *(const f32x4*)row;
  f32x4 v1 = *(const f32x4*)(row + 4);
  float vv[8] = {v0[0], v0[1], v0[2], v0[3], v1[0], v1[1], v1[2], v1[3]};

  f16x8 r;
#pragma unroll
  for (int p = 0; p < 8; ++p) {
    float cc = -128.f * vv[p];     // (-2*cb) * 64, exact pow2 scaling
    f16 hh = (f16)cc;
    r[p] = (g < 2) ? hh : (f16)(cc - (float)hh);
  }
  *(f16x8*)(cbA + ((size_t)ct * 64 + l) * 8) = r;

  if (g == 0) {
    const f32x4* rw = (const f32x4*)(cb + (size_t)code * DC);
    f32x4 a0 = rw[0], a1 = rw[1], a2 = rw[2], a3 = rw[3];
    float s = 0.f;
#pragma unroll
    for (int p = 0; p < 4; ++p)
      s += a0[p] * a0[p] + a1[p] * a1[p] + a2[p] * a2[p] + a3[p] * a3[p];
    c2s[code] = (s + 16.5f) * SCALE;
  }
}

// ---------------------------------------------------------------------------
// Kernel 2: projection + LayerNorm, emits h in MFMA-B fragment order, fp16
// hi/lo split, scaled by 256 (exact). Block = 16 tokens = one B token-tile.
// B-frag: lane l holds slots s=(l>>4)*8+p for col=l&15 (token).
// Logical: s<16 -> hi(256*h dim s), s>=16 -> lo(dim s-16).
// ---------------------------------------------------------------------------
__global__ __launch_bounds__(256) void proj_ln(const float* __restrict__ x,
                                               const float* __restrict__ w,
                                               f16* __restrict__ hB) {
  __shared__ float xs[16 * 512];    // 32 KB
  __shared__ float wsh[16 * 516];   // ~33 KB, padded pitch
  __shared__ float hsm[16][17];
  const int tid = threadIdx.x;
  const size_t base = (size_t)blockIdx.x * (16 * 512);

  const float4* xg = (const float4*)(x + base);
  float4* xs4 = (float4*)xs;
#pragma unroll
  for (int i = 0; i < 8; ++i) xs4[tid + 256 * i] = xg[tid + 256 * i];

  const float4* wg = (const float4*)w;
#pragma unroll
  for (int i = 0; i < 8; ++i) {
    int idx = tid + 256 * i;   // float4 index, 0..2047
    int c = idx >> 7;
    int d4 = idx & 127;
    *(float4*)&wsh[c * 516 + d4 * 4] = wg[idx];
  }
  __syncthreads();

  const int tok = tid >> 4;
  const int c = tid & 15;
  const float4* xr = (const float4*)(xs + tok * 512);
  const float4* wr = (const float4*)(wsh + c * 516);
  float acc0 = 0.f, acc1 = 0.f, acc2 = 0.f, acc3 = 0.f;
#pragma unroll 16
  for (int d4 = 0; d4 < 128; ++d4) {
    float4 xv = xr[d4];
    float4 wv = wr[d4];
    acc0 = fmaf(xv.x, wv.x, acc0);
    acc1 = fmaf(xv.y, wv.y, acc1);
    acc2 = fmaf(xv.z, wv.z, acc2);
    acc3 = fmaf(xv.w, wv.w, acc3);
  }
  float hv = (acc0 + acc1) + (acc2 + acc3);

  float s = hv;
  s += __shfl_xor(s, 1, 16);
  s += __shfl_xor(s, 2, 16);
  s += __shfl_xor(s, 4, 16);
  s += __shfl_xor(s, 8, 16);
  float mu = s * (1.f / 16.f);
  float diff = hv - mu;
  float v = diff * diff;
  v += __shfl_xor(v, 1, 16);
  v += __shfl_xor(v, 2, 16);
  v += __shfl_xor(v, 4, 16);
  v += __shfl_xor(v, 8, 16);
  float var = v * (1.f / 16.f);
  hsm[tok][c] = diff / sqrtf(var + LN_EPS);
  __syncthreads();

  // emit B fragment: thread -> (lane l = tid>>2, pair q = tid&3)
  const int l = tid >> 2;
  const int q = tid & 3;
  const int col = l & 15;
  const int g = l >> 4;
  const int s0 = g * 8 + q * 2;
  f16x2 u;
#pragma unroll
  for (int e = 0; e < 2; ++e) {
    int sE = s0 + e;
    int d = sE & 15;
    float f = hsm[col][d] * 256.f;   // exact pow2 scale
    f16 hh = (f16)f;
    u[e] = (sE < 16) ? hh : (f16)(f - (float)hh);
  }
  *(f16x2*)(hB + ((size_t)blockIdx.x * 64 + l) * 8 + q * 2) = u;
}

// ---------------------------------------------------------------------------
// Kernel 3: MFMA argmin. Block = 4 waves x 4 token-tiles each (256 tokens),
// all waves iterate the same KCHUNK codes (LDS-staged, double-buffered via
// global_load_lds). Per code-tile: acc = mfma(a, b1, c2) ; acc = mfma(a, b2,
// acc) -> exact (hi+lo)x(hi+lo) product. Running (best,bidx) per lane, merged
// across lane groups by shfl_xor, then packed u64 atomicMin across splits.
// ---------------------------------------------------------------------------
__global__ __launch_bounds__(256, 4) void argmin_mfma(
    const f16* __restrict__ cbA, const float* __restrict__ c2s,
    const f16* __restrict__ hB, ull* __restrict__ keys) {
  __shared__ f16 lA[2][CH * 32];   // 2 x 8 KB
  __shared__ float c2l[KCHUNK];    // 2 KB
  const int tid = threadIdx.x;
  const int w = tid >> 6;
  const int lane = tid & 63;
  const int kt0 = blockIdx.y * (KCHUNK / 16);  // first code-tile of split

  auto stage = [&](int buf, int ch) {
    const char* g = (const char*)(cbA + (size_t)(kt0 + ch * 8) * 64 * 8);
    char* lbase = (char*)&lA[buf][0];
#pragma unroll
    for (int r = 0; r < 2; ++r) {
      int bo = (r * 4 + w) * 1024 + lane * 16;
      __builtin_amdgcn_global_load_lds(
          (const __attribute__((address_space(1))) void*)(g + bo),
          (__attribute__((address_space(3))) void*)(lbase + bo), 16, 0, 0);
    }
  };

  stage(0, 0);  // issue first; L2 latency overlaps the register prologue

  // stage this split's c2 (512 floats) once
  *(float2*)&c2l[tid * 2] =
      *(const float2*)&c2s[blockIdx.y * KCHUNK + tid * 2];

  // B fragments: 4 token-tiles per wave; b2 = b1 loaded at lane^32 (=[lo|hi])
  f16x8 b1[4], b2[4];
  int ttg[4];
#pragma unroll
  for (int j = 0; j < 4; ++j) {
    ttg[j] = blockIdx.x * 16 + w * 4 + j;
    b1[j] = *(const f16x8*)&hB[((size_t)ttg[j] * 64 + lane) * 8];
    b2[j] = *(const f16x8*)&hB[((size_t)ttg[j] * 64 + (lane ^ 32)) * 8];
  }

  float best[4] = {3.0e38f, 3.0e38f, 3.0e38f, 3.0e38f};
  int bidx[4] = {0, 0, 0, 0};

  for (int ch = 0; ch < NCH; ++ch) {
    __syncthreads();  // compiler drains vmcnt+lgkmcnt before s_barrier
    if (ch + 1 < NCH) stage((ch + 1) & 1, ch + 1);
    const int buf = ch & 1;
    for (int t = 0; t < 8; ++t) {
      f16x8 a = *(const f16x8*)&lA[buf][(t * 64 + lane) * 8];
      const int lk = ch * CH + t * 16 + (lane >> 4) * 4;
      f32x4 c2v = *(const f32x4*)&c2l[lk];
      const int ib = blockIdx.y * KCHUNK + lk;
#pragma unroll
      for (int j = 0; j < 4; ++j) {
        f32x4 acc =
            __builtin_amdgcn_mfma_f32_16x16x32_f16(a, b1[j], c2v, 0, 0, 0);
        acc = __builtin_amdgcn_mfma_f32_16x16x32_f16(a, b2[j], acc, 0, 0, 0);
#pragma unroll
        for (int r = 0; r < 4; ++r) {
          bool lt = acc[r] < best[j];     // strict <, ascending k order
          best[j] = lt ? acc[r] : best[j];
          bidx[j] = lt ? (ib + r) : bidx[j];
        }
      }
    }
  }

  // merge the 4 lane-groups (rows) per token column, then global atomicMin
#pragma unroll
  for (int j = 0; j < 4; ++j) {
    float d = best[j];
    int ix = bidx[j];
#pragma unroll
    for (int off = 16; off <= 32; off <<= 1) {
      float od = __shfl_xor(d, off);
      int oi = __shfl_xor(ix, off);
      bool take = (od < d) || (od == d && oi < ix);
      d = take ? od : d;
      ix = take ? oi : ix;
    }
    d = fmaxf(d, 0.f);  // keep sign bit clear for monotone bit-packing
    if (lane < 16) {
      ull key = ((ull)__float_as_uint(d) << 32) | (unsigned)ix;
      atomicMin(&keys[ttg[j] * 16 + lane], key);
    }
  }
}

// ---------------------------------------------------------------------------
// Kernel 4: unpack code index from packed key.
// ---------------------------------------------------------------------------
__global__ __launch_bounds__(256) void finalize(const ull* __restrict__ keys,
                                                int* __restrict__ out) {
  int t = blockIdx.x * 256 + threadIdx.x;
  out[t] = (int)(unsigned)(keys[t] & 0xFFFFFFFFull);
}

// ---------------------------------------------------------------------------
extern "C" void kernel_launch(void* const* d_in, const int* in_sizes, int n_in,
                              void* d_out, int out_size, void* d_ws,
                              size_t ws_size, hipStream_t stream) {
  const float* x = (const float*)d_in[0];    // (8,2048,512)
  const float* w = (const float*)d_in[1];    // (16,512)
  const float* cb = (const float*)d_in[2];   // (8192,16)

  f16* cbA = (f16*)d_ws;                         // 8192*32 halves = 512 KB
  float* c2s = (float*)(cbA + (size_t)K * 32);   // 32 KB
  f16* hB = (f16*)(c2s + K);                     // 16384*32 halves = 1 MB
  ull* keys = (ull*)(hB + (size_t)NTOK * 32);    // 128 KB

  prep_cb<<<K / 64, 256, 0, stream>>>(cb, cbA, c2s, keys);
  proj_ln<<<NTOK / 16, 256, 0, stream>>>(x, w, hB);
  argmin_mfma<<<dim3(NTOK / 256, KSPLIT), 256, 0, stream>>>(cbA, c2s, hB,
                                                            keys);
  finalize<<<NTOK / 256, 256, 0, stream>>>(keys, (int*)d_out);
}